// Round 6
// baseline (441.645 us; speedup 1.0000x reference)
//
#include <hip/hip_runtime.h>
#include <math.h>

#define BINS 10
#define NBLOCKS 1024
#define THREADS 256

// Prefix-form partials: sum[k]/cnt[k] accumulate over elements with g >= k/10
// (i.e. s >= logit(k/10)). Per-bin values recovered in finalize via adjacent diff.
struct Partial {
    float        sum[BINS];
    unsigned int cnt[BINS];
};

// logit(k/10) = ln(k/(10-k)), k=1..9
__device__ __constant__ const float TH[9] = {
    -2.1972245773f, -1.3862943611f, -0.8472978604f, -0.4054651081f, 0.0f,
     0.4054651081f,  0.8472978604f,  1.3862943611f,  2.1972245773f
};

// s = x*(1-2t): g = sigmoid(s), bce = softplus(s) = max(s,0)+log1p(exp(-|s|)).
// Fast path: all lanes valid (wave-uniform) — no validity cndmasks, C[0] const add.
__device__ __forceinline__ void accum_fast(float x, float t,
                                           float (&A)[BINS], unsigned int (&C)[BINS]) {
    float s   = __builtin_fmaf(-2.0f * t, x, x);   // x - 2tx
    float ax  = __builtin_fabsf(x);
    float e   = __expf(-ax);
    float bce = fmaxf(s, 0.0f) + __logf(1.0f + e);
    A[0] += bce;
    C[0] += 64u;                                    // full wave valid
#pragma unroll
    for (int k = 1; k < BINS; ++k) {
        bool m = (s >= TH[k - 1]);
        A[k] += m ? bce : 0.0f;                     // v_cmp (shared) + cndmask + add
        C[k] += (unsigned int)__popcll(__ballot(m));// SALU: s_bcnt1 + s_add
    }
}

__device__ __forceinline__ void accum_slow(float x, float t, float w,
                                           float (&A)[BINS], unsigned int (&C)[BINS]) {
    float s   = __builtin_fmaf(-2.0f * t, x, x);
    float ax  = __builtin_fabsf(x);
    float e   = __expf(-ax);
    float bce = fmaxf(s, 0.0f) + __logf(1.0f + e);
    bool valid = (w > 0.0f);
    bce = valid ? bce : 0.0f;
    float sv = valid ? s : -1e30f;
    A[0] += bce;
    C[0] += (unsigned int)__popcll(__ballot(valid));
#pragma unroll
    for (int k = 1; k < BINS; ++k) {
        bool m = (sv >= TH[k - 1]);
        A[k] += m ? bce : 0.0f;
        C[k] += (unsigned int)__popcll(__ballot(m));
    }
}

__device__ __forceinline__ void accum4(const float4& p, const float4& t, const float4& w,
                                       float (&A)[BINS], unsigned int (&C)[BINS]) {
    float mw = fminf(fminf(w.x, w.y), fminf(w.z, w.w));
    if (__all(mw > 0.0f)) {                        // wave-uniform branch
        accum_fast(p.x, t.x, A, C);
        accum_fast(p.y, t.y, A, C);
        accum_fast(p.z, t.z, A, C);
        accum_fast(p.w, t.w, A, C);
    } else {
        accum_slow(p.x, t.x, w.x, A, C);
        accum_slow(p.y, t.y, w.y, A, C);
        accum_slow(p.z, t.z, w.z, A, C);
        accum_slow(p.w, t.w, w.w, A, C);
    }
}

__global__ __launch_bounds__(THREADS, 4) void ghmc_main(const float* __restrict__ pred,
                                                        const float* __restrict__ target,
                                                        const float* __restrict__ lw,
                                                        Partial* __restrict__ part,
                                                        long long total) {
    float        A[BINS];
    unsigned int C[BINS];
#pragma unroll
    for (int b = 0; b < BINS; ++b) { A[b] = 0.0f; C[b] = 0u; }

    const int tid = threadIdx.x;
    const long long nvec   = total >> 2;
    const long long stride = (long long)NBLOCKS * THREADS;   // 262144
    const float4* __restrict__ P = reinterpret_cast<const float4*>(pred);
    const float4* __restrict__ T = reinterpret_cast<const float4*>(target);
    const float4* __restrict__ W = reinterpret_cast<const float4*>(lw);

    // 2-deep pair pipeline: 6 dwordx4 loads in flight while 8 elements compute
    long long i = (long long)blockIdx.x * THREADS + tid;
    if (i + stride < nvec) {
        float4 pa0 = P[i], ta0 = T[i], wa0 = W[i];
        float4 pa1 = P[i + stride], ta1 = T[i + stride], wa1 = W[i + stride];
        i += 2 * stride;
        for (; i + stride < nvec; i += 2 * stride) {
            float4 pb0 = P[i], tb0 = T[i], wb0 = W[i];
            float4 pb1 = P[i + stride], tb1 = T[i + stride], wb1 = W[i + stride];
            accum4(pa0, ta0, wa0, A, C);
            accum4(pa1, ta1, wa1, A, C);
            pa0 = pb0; ta0 = tb0; wa0 = wb0;
            pa1 = pb1; ta1 = tb1; wa1 = wb1;
        }
        accum4(pa0, ta0, wa0, A, C);
        accum4(pa1, ta1, wa1, A, C);
    }
    for (; i < nvec; i += stride) {                 // leftover single strides
        float4 p = P[i], t = T[i], w = W[i];
        accum4(p, t, w, A, C);
    }

    // scalar tail (total % 4): block 0 only
    const long long base = nvec << 2;
    const int rem = (int)(total - base);
    if (blockIdx.x == 0 && tid < rem)
        accum_slow(pred[base + tid], target[base + tid], lw[base + tid], A, C);

    // sums: wave butterfly; counts already wave-uniform (ballot path)
#pragma unroll
    for (int b = 0; b < BINS; ++b) {
#pragma unroll
        for (int off = 32; off; off >>= 1)
            A[b] += __shfl_xor(A[b], off, 64);
    }

    __shared__ float        ls[THREADS / 64][BINS];
    __shared__ unsigned int lc[THREADS / 64][BINS];
    const int wid  = tid >> 6;
    const int lane = tid & 63;
    if (lane == 0) {
#pragma unroll
        for (int b = 0; b < BINS; ++b) { ls[wid][b] = A[b]; lc[wid][b] = C[b]; }
    }
    __syncthreads();

    if (tid < BINS) {
        float sb = 0.0f; unsigned int cb = 0u;
#pragma unroll
        for (int w2 = 0; w2 < THREADS / 64; ++w2) { sb += ls[w2][tid]; cb += lc[w2][tid]; }
        part[blockIdx.x].sum[tid] = sb;   // plain store, no atomics
        part[blockIdx.x].cnt[tid] = cb;
    }
}

__global__ __launch_bounds__(THREADS) void ghmc_finalize(const Partial* __restrict__ part,
                                                         float* __restrict__ out,
                                                         int nblocks) {
    double             acc[BINS];
    unsigned long long cn[BINS];
#pragma unroll
    for (int b = 0; b < BINS; ++b) { acc[b] = 0.0; cn[b] = 0ull; }

    const int tid = threadIdx.x;
    for (int i = tid; i < nblocks; i += THREADS) {
#pragma unroll
        for (int b = 0; b < BINS; ++b) {
            acc[b] += (double)part[i].sum[b];
            cn[b]  += (unsigned long long)part[i].cnt[b];
        }
    }
#pragma unroll
    for (int b = 0; b < BINS; ++b) {
#pragma unroll
        for (int off = 32; off; off >>= 1) {
            acc[b] += __shfl_xor(acc[b], off, 64);
            cn[b]  += __shfl_xor(cn[b], off, 64);
        }
    }

    __shared__ double             lds_s[THREADS / 64][BINS];
    __shared__ unsigned long long lds_c[THREADS / 64][BINS];
    const int wid  = tid >> 6;
    const int lane = tid & 63;
    if (lane == 0) {
#pragma unroll
        for (int b = 0; b < BINS; ++b) { lds_s[wid][b] = acc[b]; lds_c[wid][b] = cn[b]; }
    }
    __syncthreads();

    if (tid == 0) {
        double pS[BINS + 1];
        double pC[BINS + 1];
        for (int b = 0; b < BINS; ++b) {
            double sb = 0.0; unsigned long long cb = 0ull;
            for (int w2 = 0; w2 < THREADS / 64; ++w2) { sb += lds_s[w2][b]; cb += lds_c[w2][b]; }
            pS[b] = sb; pC[b] = (double)cb;
        }
        pS[BINS] = 0.0; pC[BINS] = 0.0;
        double loss = 0.0;
        int n = 0;
        for (int b = 0; b < BINS; ++b) {
            double cb = pC[b] - pC[b + 1];      // prefix -> per-bin
            double sb = pS[b] - pS[b + 1];
            if (cb > 0.0) { loss += sb / cb; ++n; }
        }
        double denom = (n > 0) ? (double)n : 1.0;
        out[0] = (float)(loss / denom);   // LOSS_WEIGHT == 1.0; tot cancels algebraically
    }
}

extern "C" void kernel_launch(void* const* d_in, const int* in_sizes, int n_in,
                              void* d_out, int out_size, void* d_ws, size_t ws_size,
                              hipStream_t stream) {
    const float* pred   = (const float*)d_in[0];
    const float* target = (const float*)d_in[1];
    const float* lw     = (const float*)d_in[2];
    float* out = (float*)d_out;
    Partial* part = (Partial*)d_ws;
    const long long total = (long long)in_sizes[0];

    ghmc_main<<<NBLOCKS, THREADS, 0, stream>>>(pred, target, lw, part, total);
    ghmc_finalize<<<1, THREADS, 0, stream>>>(part, out, NBLOCKS);
}

// Round 7
// 441.577 us; speedup vs baseline: 1.0002x; 1.0002x over previous
//
#include <hip/hip_runtime.h>
#include <math.h>

#define BINS 10
#define NBLOCKS 2048
#define THREADS 256

// Prefix-form partials: sum[k]/cnt[k] accumulate over elements with g >= k/10
// (i.e. s >= logit(k/10)). Per-bin values recovered in finalize via adjacent diff.
struct Partial {
    float        sum[BINS];
    unsigned int cnt[BINS];
};

// logit(k/10) = ln(k/(10-k)), k=1..9
__device__ __constant__ const float TH[9] = {
    -2.1972245773f, -1.3862943611f, -0.8472978604f, -0.4054651081f, 0.0f,
     0.4054651081f,  0.8472978604f,  1.3862943611f,  2.1972245773f
};

// s = x*(1-2t): g = sigmoid(s), bce = softplus(s) = max(s,0)+log1p(exp(-|s|)).
__device__ __forceinline__ void accum_fast(float x, float t,
                                           float (&A)[BINS], unsigned int (&C)[BINS]) {
    float s   = __builtin_fmaf(-2.0f * t, x, x);   // x - 2tx
    float ax  = __builtin_fabsf(x);
    float e   = __expf(-ax);
    float bce = fmaxf(s, 0.0f) + __logf(1.0f + e);
    A[0] += bce;
    C[0] += 64u;                                    // full wave valid
#pragma unroll
    for (int k = 1; k < BINS; ++k) {
        bool m = (s >= TH[k - 1]);
        A[k] += m ? bce : 0.0f;                     // v_cmp + cndmask + add
        C[k] += (unsigned int)__popcll(__ballot(m));// SALU: s_bcnt1 + s_add
    }
}

__device__ __forceinline__ void accum_slow(float x, float t, float w,
                                           float (&A)[BINS], unsigned int (&C)[BINS]) {
    float s   = __builtin_fmaf(-2.0f * t, x, x);
    float ax  = __builtin_fabsf(x);
    float e   = __expf(-ax);
    float bce = fmaxf(s, 0.0f) + __logf(1.0f + e);
    bool valid = (w > 0.0f);
    bce = valid ? bce : 0.0f;
    float sv = valid ? s : -1e30f;
    A[0] += bce;
    C[0] += (unsigned int)__popcll(__ballot(valid));
#pragma unroll
    for (int k = 1; k < BINS; ++k) {
        bool m = (sv >= TH[k - 1]);
        A[k] += m ? bce : 0.0f;
        C[k] += (unsigned int)__popcll(__ballot(m));
    }
}

__device__ __forceinline__ void accum4(const float4& p, const float4& t, const float4& w,
                                       float (&A)[BINS], unsigned int (&C)[BINS]) {
    float mw = fminf(fminf(w.x, w.y), fminf(w.z, w.w));
    if (__all(mw > 0.0f)) {                        // wave-uniform branch
        accum_fast(p.x, t.x, A, C);
        accum_fast(p.y, t.y, A, C);
        accum_fast(p.z, t.z, A, C);
        accum_fast(p.w, t.w, A, C);
    } else {
        accum_slow(p.x, t.x, w.x, A, C);
        accum_slow(p.y, t.y, w.y, A, C);
        accum_slow(p.z, t.z, w.z, A, C);
        accum_slow(p.w, t.w, w.w, A, C);
    }
}

__global__ __launch_bounds__(THREADS) void ghmc_main(const float* __restrict__ pred,
                                                     const float* __restrict__ target,
                                                     const float* __restrict__ lw,
                                                     Partial* __restrict__ part,
                                                     long long total) {
    float        A[BINS];
    unsigned int C[BINS];
#pragma unroll
    for (int b = 0; b < BINS; ++b) { A[b] = 0.0f; C[b] = 0u; }

    const int tid = threadIdx.x;
    const long long nvec   = total >> 2;
    const long long stride = (long long)NBLOCKS * THREADS;
    const float4* __restrict__ P = reinterpret_cast<const float4*>(pred);
    const float4* __restrict__ T = reinterpret_cast<const float4*>(target);
    const float4* __restrict__ W = reinterpret_cast<const float4*>(lw);

    // 1-deep register prefetch. The asm memory fence pins the next-batch loads
    // ABOVE the current batch's compute: the compiler cannot sink them to
    // just-before-use, so 3 dwordx4 stay in flight under ~300 cyc of VALU.
    long long i = (long long)blockIdx.x * THREADS + tid;
    const bool have = (i < nvec);
    float4 pa, ta, wa;
    if (have) { pa = P[i]; ta = T[i]; wa = W[i]; }
    for (long long j = i + stride; j < nvec; j += stride) {
        float4 pb = P[j], tb = T[j], wb = W[j];
        asm volatile("" ::: "memory");             // scheduling fence (no code)
        accum4(pa, ta, wa, A, C);
        pa = pb; ta = tb; wa = wb;
    }
    if (have) accum4(pa, ta, wa, A, C);

    // scalar tail (total % 4): block 0 only
    const long long base = nvec << 2;
    const int rem = (int)(total - base);
    if (blockIdx.x == 0 && tid < rem)
        accum_slow(pred[base + tid], target[base + tid], lw[base + tid], A, C);

    // sums: wave butterfly; counts already wave-uniform (ballot path)
#pragma unroll
    for (int b = 0; b < BINS; ++b) {
#pragma unroll
        for (int off = 32; off; off >>= 1)
            A[b] += __shfl_xor(A[b], off, 64);
    }

    __shared__ float        ls[THREADS / 64][BINS];
    __shared__ unsigned int lc[THREADS / 64][BINS];
    const int wid  = tid >> 6;
    const int lane = tid & 63;
    if (lane == 0) {
#pragma unroll
        for (int b = 0; b < BINS; ++b) { ls[wid][b] = A[b]; lc[wid][b] = C[b]; }
    }
    __syncthreads();

    if (tid < BINS) {
        float sb = 0.0f; unsigned int cb = 0u;
#pragma unroll
        for (int w2 = 0; w2 < THREADS / 64; ++w2) { sb += ls[w2][tid]; cb += lc[w2][tid]; }
        part[blockIdx.x].sum[tid] = sb;   // plain store, no atomics
        part[blockIdx.x].cnt[tid] = cb;
    }
}

__global__ __launch_bounds__(THREADS) void ghmc_finalize(const Partial* __restrict__ part,
                                                         float* __restrict__ out,
                                                         int nblocks) {
    double             acc[BINS];
    unsigned long long cn[BINS];
#pragma unroll
    for (int b = 0; b < BINS; ++b) { acc[b] = 0.0; cn[b] = 0ull; }

    const int tid = threadIdx.x;
    for (int i = tid; i < nblocks; i += THREADS) {
#pragma unroll
        for (int b = 0; b < BINS; ++b) {
            acc[b] += (double)part[i].sum[b];
            cn[b]  += (unsigned long long)part[i].cnt[b];
        }
    }
#pragma unroll
    for (int b = 0; b < BINS; ++b) {
#pragma unroll
        for (int off = 32; off; off >>= 1) {
            acc[b] += __shfl_xor(acc[b], off, 64);
            cn[b]  += __shfl_xor(cn[b], off, 64);
        }
    }

    __shared__ double             lds_s[THREADS / 64][BINS];
    __shared__ unsigned long long lds_c[THREADS / 64][BINS];
    const int wid  = tid >> 6;
    const int lane = tid & 63;
    if (lane == 0) {
#pragma unroll
        for (int b = 0; b < BINS; ++b) { lds_s[wid][b] = acc[b]; lds_c[wid][b] = cn[b]; }
    }
    __syncthreads();

    if (tid == 0) {
        double pS[BINS + 1];
        double pC[BINS + 1];
        for (int b = 0; b < BINS; ++b) {
            double sb = 0.0; unsigned long long cb = 0ull;
            for (int w2 = 0; w2 < THREADS / 64; ++w2) { sb += lds_s[w2][b]; cb += lds_c[w2][b]; }
            pS[b] = sb; pC[b] = (double)cb;
        }
        pS[BINS] = 0.0; pC[BINS] = 0.0;
        double loss = 0.0;
        int n = 0;
        for (int b = 0; b < BINS; ++b) {
            double cb = pC[b] - pC[b + 1];      // prefix -> per-bin
            double sb = pS[b] - pS[b + 1];
            if (cb > 0.0) { loss += sb / cb; ++n; }
        }
        double denom = (n > 0) ? (double)n : 1.0;
        out[0] = (float)(loss / denom);   // LOSS_WEIGHT == 1.0; tot cancels algebraically
    }
}

extern "C" void kernel_launch(void* const* d_in, const int* in_sizes, int n_in,
                              void* d_out, int out_size, void* d_ws, size_t ws_size,
                              hipStream_t stream) {
    const float* pred   = (const float*)d_in[0];
    const float* target = (const float*)d_in[1];
    const float* lw     = (const float*)d_in[2];
    float* out = (float*)d_out;
    Partial* part = (Partial*)d_ws;
    const long long total = (long long)in_sizes[0];

    ghmc_main<<<NBLOCKS, THREADS, 0, stream>>>(pred, target, lw, part, total);
    ghmc_finalize<<<1, THREADS, 0, stream>>>(part, out, NBLOCKS);
}

// Round 9
// 419.370 us; speedup vs baseline: 1.0531x; 1.0530x over previous
//
#include <hip/hip_runtime.h>
#include <math.h>

#define BINS 10
#define NBLOCKS 2048
#define THREADS 256

typedef float f32x4 __attribute__((ext_vector_type(4)));   // nontemporal-load-compatible

// Prefix-form partials: sum[k]/cnt[k] accumulate over elements with g >= k/10
// (i.e. s >= logit(k/10)). Per-bin values recovered in finalize via adjacent diff.
struct Partial {
    float        sum[BINS];
    unsigned int cnt[BINS];
};

// logit(k/10) = ln(k/(10-k)), k=1..9
__device__ __constant__ const float TH[9] = {
    -2.1972245773f, -1.3862943611f, -0.8472978604f, -0.4054651081f, 0.0f,
     0.4054651081f,  0.8472978604f,  1.3862943611f,  2.1972245773f
};

// s = x*(1-2t): g = sigmoid(s), bce = softplus(s) = max(s,0)+log1p(exp(-|s|)).
// Exact identities with the reference's stable-BCE form (|s| == |x|).
__device__ __forceinline__ void accum_one(float x, float t, float w,
                                          float (&A)[BINS], unsigned int (&C)[BINS]) {
    float s   = __builtin_fmaf(-2.0f * t, x, x);   // x - 2tx
    float ax  = __builtin_fabsf(x);
    float e   = __expf(-ax);
    float bce = fmaxf(s, 0.0f) + __logf(1.0f + e);
    bool valid = (w > 0.0f);
    bce = valid ? bce : 0.0f;
    float sv = valid ? s : -1e30f;                 // fails every threshold
    A[0] += bce;
    C[0] += (unsigned int)__popcll(__ballot(valid));
#pragma unroll
    for (int k = 1; k < BINS; ++k) {
        bool m = (sv >= TH[k - 1]);
        A[k] += m ? bce : 0.0f;                    // shared v_cmp + cndmask + add
        C[k] += (unsigned int)__popcll(__ballot(m));   // SALU: s_bcnt1 + s_add
    }
}

__device__ __forceinline__ void accum4(const f32x4& p, const f32x4& t, const f32x4& w,
                                       float (&A)[BINS], unsigned int (&C)[BINS]) {
    accum_one(p.x, t.x, w.x, A, C);
    accum_one(p.y, t.y, w.y, A, C);
    accum_one(p.z, t.z, w.z, A, C);
    accum_one(p.w, t.w, w.w, A, C);
}

__global__ __launch_bounds__(THREADS) void ghmc_main(const float* __restrict__ pred,
                                                     const float* __restrict__ target,
                                                     const float* __restrict__ lw,
                                                     Partial* __restrict__ part,
                                                     long long total) {
    float        A[BINS];
    unsigned int C[BINS];
#pragma unroll
    for (int b = 0; b < BINS; ++b) { A[b] = 0.0f; C[b] = 0u; }

    const int tid = threadIdx.x;
    const long long nv8    = total >> 3;           // 32B chunks (2x float4)
    const long long stride = (long long)NBLOCKS * THREADS;
    const f32x4* __restrict__ P = reinterpret_cast<const f32x4*>(pred);
    const f32x4* __restrict__ T = reinterpret_cast<const f32x4*>(target);
    const f32x4* __restrict__ W = reinterpret_cast<const f32x4*>(lw);

    // Each iteration: 6 independent nontemporal dwordx4 loads (6 KB/wave in
    // flight) with no use in between — structural MLP the scheduler can't undo.
    for (long long i = (long long)blockIdx.x * THREADS + tid; i < nv8; i += stride) {
        const long long v = 2 * i;
        f32x4 p0 = __builtin_nontemporal_load(&P[v]);
        f32x4 p1 = __builtin_nontemporal_load(&P[v + 1]);
        f32x4 t0 = __builtin_nontemporal_load(&T[v]);
        f32x4 t1 = __builtin_nontemporal_load(&T[v + 1]);
        f32x4 w0 = __builtin_nontemporal_load(&W[v]);
        f32x4 w1 = __builtin_nontemporal_load(&W[v + 1]);
        accum4(p0, t0, w0, A, C);
        accum4(p1, t1, w1, A, C);
    }

    // scalar tail (total % 8): block 0 only
    const long long base = nv8 << 3;
    const int rem = (int)(total - base);
    if (blockIdx.x == 0 && tid < rem)
        accum_one(pred[base + tid], target[base + tid], lw[base + tid], A, C);

    // sums: wave butterfly; counts already wave-uniform (ballot path)
#pragma unroll
    for (int b = 0; b < BINS; ++b) {
#pragma unroll
        for (int off = 32; off; off >>= 1)
            A[b] += __shfl_xor(A[b], off, 64);
    }

    __shared__ float        ls[THREADS / 64][BINS];
    __shared__ unsigned int lc[THREADS / 64][BINS];
    const int wid  = tid >> 6;
    const int lane = tid & 63;
    if (lane == 0) {
#pragma unroll
        for (int b = 0; b < BINS; ++b) { ls[wid][b] = A[b]; lc[wid][b] = C[b]; }
    }
    __syncthreads();

    if (tid < BINS) {
        float sb = 0.0f; unsigned int cb = 0u;
#pragma unroll
        for (int w2 = 0; w2 < THREADS / 64; ++w2) { sb += ls[w2][tid]; cb += lc[w2][tid]; }
        part[blockIdx.x].sum[tid] = sb;   // plain store, no atomics
        part[blockIdx.x].cnt[tid] = cb;
    }
}

__global__ __launch_bounds__(THREADS) void ghmc_finalize(const Partial* __restrict__ part,
                                                         float* __restrict__ out,
                                                         int nblocks) {
    double             acc[BINS];
    unsigned long long cn[BINS];
#pragma unroll
    for (int b = 0; b < BINS; ++b) { acc[b] = 0.0; cn[b] = 0ull; }

    const int tid = threadIdx.x;
    for (int i = tid; i < nblocks; i += THREADS) {
#pragma unroll
        for (int b = 0; b < BINS; ++b) {
            acc[b] += (double)part[i].sum[b];
            cn[b]  += (unsigned long long)part[i].cnt[b];
        }
    }
#pragma unroll
    for (int b = 0; b < BINS; ++b) {
#pragma unroll
        for (int off = 32; off; off >>= 1) {
            acc[b] += __shfl_xor(acc[b], off, 64);
            cn[b]  += __shfl_xor(cn[b], off, 64);
        }
    }

    __shared__ double             lds_s[THREADS / 64][BINS];
    __shared__ unsigned long long lds_c[THREADS / 64][BINS];
    const int wid  = tid >> 6;
    const int lane = tid & 63;
    if (lane == 0) {
#pragma unroll
        for (int b = 0; b < BINS; ++b) { lds_s[wid][b] = acc[b]; lds_c[wid][b] = cn[b]; }
    }
    __syncthreads();

    if (tid == 0) {
        double pS[BINS + 1];
        double pC[BINS + 1];
        for (int b = 0; b < BINS; ++b) {
            double sb = 0.0; unsigned long long cb = 0ull;
            for (int w2 = 0; w2 < THREADS / 64; ++w2) { sb += lds_s[w2][b]; cb += lds_c[w2][b]; }
            pS[b] = sb; pC[b] = (double)cb;
        }
        pS[BINS] = 0.0; pC[BINS] = 0.0;
        double loss = 0.0;
        int n = 0;
        for (int b = 0; b < BINS; ++b) {
            double cb = pC[b] - pC[b + 1];      // prefix -> per-bin
            double sb = pS[b] - pS[b + 1];
            if (cb > 0.0) { loss += sb / cb; ++n; }
        }
        double denom = (n > 0) ? (double)n : 1.0;
        out[0] = (float)(loss / denom);   // LOSS_WEIGHT == 1.0; tot cancels algebraically
    }
}

extern "C" void kernel_launch(void* const* d_in, const int* in_sizes, int n_in,
                              void* d_out, int out_size, void* d_ws, size_t ws_size,
                              hipStream_t stream) {
    const float* pred   = (const float*)d_in[0];
    const float* target = (const float*)d_in[1];
    const float* lw     = (const float*)d_in[2];
    float* out = (float*)d_out;
    Partial* part = (Partial*)d_ws;
    const long long total = (long long)in_sizes[0];

    ghmc_main<<<NBLOCKS, THREADS, 0, stream>>>(pred, target, lw, part, total);
    ghmc_finalize<<<1, THREADS, 0, stream>>>(part, out, NBLOCKS);
}